// Round 9
// baseline (132.777 us; speedup 1.0000x reference)
//
#include <hip/hip_runtime.h>

// ---------------------------------------------------------------------------
// Fully-fused Sparse-MMoE forward for MI355X (gfx950), v9.
// B=65536, D=512, E=8, H1=64, H2=32, O=64, T=2, K=2.
//
// v9: 2048 blocks x 512 thr (8 waves = 8 experts), 32 tokens/block.
//     Register budget ~82 (50 arch + 32 acc) under launch_bounds(512,6)
//     cap 85 -> 6 waves/SIMD -> 3 blocks/CU (was 2).  Gating stays exact
//     fp32 with wave-uniform SCALAR weight loads; the per-lane k-half
//     (lane>>5) is selected via cndmask on scalar values.
//
// moe_prep:  weight repack fp32 -> bf16 MFMA B-fragment order (+ wgt fp32
//            transpose copy, + gacc/cnt zeroing).
// moe_fused: gating -> top-2 -> 3-layer bf16-MFMA expert MLP -> combine,
//            in-kernel cv^2 loss via done-counter.
// ---------------------------------------------------------------------------

typedef short bfrag __attribute__((ext_vector_type(8)));   // 8 bf16 = 4 VGPRs
typedef float facc  __attribute__((ext_vector_type(4)));   // 4 f32 accum

#define MFMA16(a, b, c) __builtin_amdgcn_mfma_f32_16x16x32_bf16((a), (b), (c), 0, 0, 0)

__device__ __forceinline__ unsigned short bfbits(float f) {
  unsigned int u = __builtin_bit_cast(unsigned int, f);
  u += 0x7FFFu + ((u >> 16) & 1u);          // RNE
  return (unsigned short)(u >> 16);
}
__device__ __forceinline__ unsigned pack2(float a, float b) {
  return (unsigned)bfbits(a) | ((unsigned)bfbits(b) << 16);
}
__device__ __forceinline__ float bf2f(unsigned short s) {
  unsigned int u = ((unsigned int)s) << 16;
  return __builtin_bit_cast(float, u);
}

// LDS map (bytes):
//  [0,     32768) : gating partials [16 c=(w,kh)][32 tok][16 slot] f32
//                   -> X tile [32 tok][512] bf16 pitch 1024, ^((tok&7)<<4)
//                   -> 8 expert chunks of 4 KB (H1 [32][64]s pitch 128 ->
//                      H2 [32][32]s2 pitch 64 front -> Out [32][64]s)
//  [32768, 34944) : G logits [32 tok][17] f32 (pitch 17: conflict-dodge)
//  [34944, 35968) : recs [32 tok][2 task] float4 {g1,g2,e1,e2}
//  [35968, 36096) : lacc [32] f32
#define G_OFF   32768
#define R_OFF   34944
#define A_OFF   35968
#define SM_SIZE 36096

__global__ __launch_bounds__(512, 6) void moe_fused(
    const float* __restrict__ x,
    const float* __restrict__ b_gates,
    const float* __restrict__ wgt,      // [16 te][512 k] f32, te = t*8+e
    const float* __restrict__ b1,
    const float* __restrict__ b2,
    const float* __restrict__ b3,
    const bfrag* __restrict__ w1f,
    const bfrag* __restrict__ w2f,
    const bfrag* __restrict__ w3f,
    float* __restrict__ gacc_out,       // [32] + cnt at +32
    float* __restrict__ y)
{
  __shared__ alignas(16) char smem[SM_SIZE];
  const int tid = threadIdx.x;
  const int wave = tid >> 6, lane = tid & 63;
  const int q = lane & 15, g = lane >> 4;
  const int e = wave;                       // 8 waves = 8 experts
  const unsigned cb = (unsigned)e * 4096u;  // own chunk
  const int tok = lane & 31;                // token (0..31)
  const int kh  = lane >> 5;                // k-half within wave's 64-chunk

  if (tid < 32) ((float*)(smem + A_OFF))[tid] = 0.f;

  // ---------- load x: thread (wave,kh,tok) holds k [wave*64+kh*32, +32) ----------
  const float* src = x + (size_t)blockIdx.x * 32 * 512 + tok * 512 + wave * 64 + kh * 32;
  float4 fr[8];
  #pragma unroll
  for (int j = 0; j < 8; ++j) fr[j] = ((const float4*)src)[j];

  // ---------- gating partial dots: exact fp32, scalar weights + kh-select ----------
  {
    int wu = __builtin_amdgcn_readfirstlane(wave);
    const float* wbase = wgt + wu * 64;
    float* pp = (float*)smem + ((wave * 2 + kh) * 32 + tok) * 16;
    #pragma unroll
    for (int te = 0; te < 16; ++te) {
      const float* wrow = wbase + te * 512;
      float a0 = 0.f, a1 = 0.f, a2 = 0.f, a3 = 0.f;
      #pragma unroll
      for (int j = 0; j < 8; ++j) {
        float4 lo = *(const float4*)(wrow + j * 4);
        float4 hi = *(const float4*)(wrow + 32 + j * 4);
        float wx = kh ? hi.x : lo.x;
        float wy = kh ? hi.y : lo.y;
        float wz = kh ? hi.z : lo.z;
        float ww = kh ? hi.w : lo.w;
        a0 = fmaf(fr[j].x, wx, a0);
        a1 = fmaf(fr[j].y, wy, a1);
        a2 = fmaf(fr[j].z, wz, a2);
        a3 = fmaf(fr[j].w, ww, a3);
      }
      pp[(te + (tok >> 1)) & 15] = (a0 + a1) + (a2 + a3);   // rotated: conflict-free
    }
  }
  __syncthreads();                                   // B0

  // ---------- reduce 16 (wave,kh) partials -> G logits (pitch 17) ----------
  {
    int tk = tid >> 4, te = tid & 15;
    const float* pb = (const float*)smem + tk * 16 + ((te + (tk >> 1)) & 15);
    float s = 0.f;
    #pragma unroll
    for (int c = 0; c < 16; ++c) s += pb[c * 512];
    ((float*)(smem + G_OFF))[tk * 17 + te] = s + b_gates[te];
  }
  __syncthreads();                                   // B1 (partials dead)

  // ---------- stage X tile from registers (bf16, swizzled) ----------
  #pragma unroll
  for (int p = 0; p < 4; ++p) {
    uint4 v;
    v.x = pack2(fr[2 * p].x, fr[2 * p].y);
    v.y = pack2(fr[2 * p].z, fr[2 * p].w);
    v.z = pack2(fr[2 * p + 1].x, fr[2 * p + 1].y);
    v.w = pack2(fr[2 * p + 1].z, fr[2 * p + 1].w);
    unsigned byte = ((unsigned)(tok * 1024 + wave * 128 + kh * 64 + p * 16)) ^ ((unsigned)(tok & 7) << 4);
    *(uint4*)(smem + byte) = v;
  }

  // ---------- top-2 + softmax -> recs + imp/load atomics ----------
  if (tid < 64) {
    int ttok = tid >> 1, task = tid & 1;
    const float* Gr = (const float*)(smem + G_OFF) + ttok * 17 + task * 8;
    float l[8];
    #pragma unroll
    for (int ee = 0; ee < 8; ++ee) l[ee] = Gr[ee];
    float v1 = l[0]; int e1 = 0;
    #pragma unroll
    for (int ee = 1; ee < 8; ++ee) { if (l[ee] > v1) { v1 = l[ee]; e1 = ee; } }
    float v2 = -3.4e38f; int e2 = 0;
    #pragma unroll
    for (int ee = 0; ee < 8; ++ee) {
      if (ee != e1 && l[ee] > v2) { v2 = l[ee]; e2 = ee; }
    }
    float g1 = 1.f / (1.f + __expf(v2 - v1));
    float g2 = 1.f - g1;
    float4 rec;
    rec.x = g1; rec.y = g2;
    rec.z = __int_as_float(e1); rec.w = __int_as_float(e2);
    ((float4*)(smem + R_OFF))[ttok * 2 + task] = rec;
    float* lacc = (float*)(smem + A_OFF);
    atomicAdd(lacc + task * 8 + e1, g1);
    atomicAdd(lacc + task * 8 + e2, g2);
    atomicAdd(lacc + 16 + task * 8 + e1, 1.f);
    atomicAdd(lacc + 16 + task * 8 + e2, 1.f);
  }
  __syncthreads();                                   // B2 (X staged)

  // ---------------- GEMM1: 32 tok x 64 h1, K=512 ----------------
  facc acc[2][4];
  #pragma unroll
  for (int m = 0; m < 2; ++m)
    #pragma unroll
    for (int n = 0; n < 4; ++n) acc[m][n] = (facc)0.f;

  const bfrag* w1e = w1f + e * 4096 + lane;
  #pragma unroll
  for (int ks = 0; ks < 16; ++ks) {
    bfrag B0 = w1e[ks * 256];
    bfrag B1 = w1e[ks * 256 + 64];
    bfrag B2 = w1e[ks * 256 + 128];
    bfrag B3 = w1e[ks * 256 + 192];
    #pragma unroll
    for (int m = 0; m < 2; ++m) {
      unsigned ba = ((unsigned)((m * 16 + q) * 1024 + ks * 64 + g * 16)) ^ ((unsigned)(q & 7) << 4);
      bfrag A = *(const bfrag*)(smem + ba);
      acc[m][0] = MFMA16(A, B0, acc[m][0]);
      acc[m][1] = MFMA16(A, B1, acc[m][1]);
      acc[m][2] = MFMA16(A, B2, acc[m][2]);
      acc[m][3] = MFMA16(A, B3, acc[m][3]);
    }
  }

  // preload GEMM2 weights + bias (in flight across barrier + H1 phase)
  bfrag W2r[4];
  #pragma unroll
  for (int i = 0; i < 4; ++i) W2r[i] = w2f[e * 256 + i * 64 + lane];
  float b2v0 = b2[e * 32 + q];
  float b2v1 = b2[e * 32 + 16 + q];
  __syncthreads();                                   // B3 (X dead)

  // ---------------- H1 -> own chunk (sigma: s = q*4+n) ----------------
  {
    float bv[4];
    #pragma unroll
    for (int n = 0; n < 4; ++n) bv[n] = b1[e * 64 + n * 16 + q];
    #pragma unroll
    for (int m = 0; m < 2; ++m) {
      #pragma unroll
      for (int j = 0; j < 4; ++j) {
        float v0 = fmaxf(acc[m][0][j] + bv[0], 0.f);
        float v1 = fmaxf(acc[m][1][j] + bv[1], 0.f);
        float v2 = fmaxf(acc[m][2][j] + bv[2], 0.f);
        float v3 = fmaxf(acc[m][3][j] + bv[3], 0.f);
        int rr = m * 16 + g * 4 + j;
        unsigned byte = cb + (((unsigned)(rr * 128 + q * 8)) ^ ((unsigned)(rr & 7) << 4));
        uint2 pk; pk.x = pack2(v0, v1); pk.y = pack2(v2, v3);
        *(uint2*)(smem + byte) = pk;
      }
    }
  }

  // ---------------- GEMM2: K=64 (sigma), N=32 ----------------
  {
    facc a2[2][2];
    #pragma unroll
    for (int m = 0; m < 2; ++m) { a2[m][0] = (facc)0.f; a2[m][1] = (facc)0.f; }
    #pragma unroll
    for (int ks = 0; ks < 2; ++ks) {
      #pragma unroll
      for (int m = 0; m < 2; ++m) {
        unsigned ba = cb + (((unsigned)((m * 16 + q) * 128 + ks * 64 + g * 16)) ^ ((unsigned)(q & 7) << 4));
        bfrag A = *(const bfrag*)(smem + ba);
        a2[m][0] = MFMA16(A, W2r[ks * 2], a2[m][0]);
        a2[m][1] = MFMA16(A, W2r[ks * 2 + 1], a2[m][1]);
      }
    }
    // preload GEMM3 weights + bias
    bfrag W3r[4];
    #pragma unroll
    for (int n = 0; n < 4; ++n) W3r[n] = w3f[e * 256 + n * 64 + lane];
    float b3v[4];
    #pragma unroll
    for (int n = 0; n < 4; ++n) b3v[n] = b3[e * 64 + n * 16 + q];

    // H2 -> own chunk front (sigma2: s = q*2+n)
    #pragma unroll
    for (int m = 0; m < 2; ++m) {
      #pragma unroll
      for (int j = 0; j < 4; ++j) {
        float v0 = fmaxf(a2[m][0][j] + b2v0, 0.f);
        float v1 = fmaxf(a2[m][1][j] + b2v1, 0.f);
        int rr = m * 16 + g * 4 + j;
        unsigned byte = cb + (((unsigned)(rr * 64 + q * 4)) ^ ((unsigned)(rr & 7) << 4));
        *(unsigned int*)(smem + byte) = pack2(v0, v1);
      }
    }

    // ---------------- GEMM3: K=32 (sigma2), N=64 ----------------
    facc a3[2][4];
    #pragma unroll
    for (int m = 0; m < 2; ++m)
      #pragma unroll
      for (int n = 0; n < 4; ++n) a3[m][n] = (facc)0.f;
    #pragma unroll
    for (int m = 0; m < 2; ++m) {
      unsigned ba = cb + (((unsigned)((m * 16 + q) * 64 + g * 16)) ^ ((unsigned)(q & 7) << 4));
      bfrag A = *(const bfrag*)(smem + ba);
      #pragma unroll
      for (int n = 0; n < 4; ++n) a3[m][n] = MFMA16(A, W3r[n], a3[m][n]);
    }
    // Out -> full own chunk (sigma: s = q*4+n), after all H2 reads (in-order)
    #pragma unroll
    for (int m = 0; m < 2; ++m) {
      #pragma unroll
      for (int j = 0; j < 4; ++j) {
        float v0 = fmaxf(a3[m][0][j] + b3v[0], 0.f);
        float v1 = fmaxf(a3[m][1][j] + b3v[1], 0.f);
        float v2 = fmaxf(a3[m][2][j] + b3v[2], 0.f);
        float v3 = fmaxf(a3[m][3][j] + b3v[3], 0.f);
        int rr = m * 16 + g * 4 + j;
        unsigned byte = cb + (((unsigned)(rr * 128 + q * 8)) ^ ((unsigned)(rr & 7) << 4));
        uint2 pk; pk.x = pack2(v0, v1); pk.y = pack2(v2, v3);
        *(uint2*)(smem + byte) = pk;
      }
    }
  }
  __syncthreads();                                   // B4

  // ---------------- combine: recs + weighted sum ----------------
  {
    int ct = tid >> 4, u = tid & 15;
    size_t trow = (size_t)blockIdx.x * 32 + ct;
    unsigned obyte = ((unsigned)(ct * 128 + u * 8)) ^ ((unsigned)(ct & 7) << 4);
    const float4* recs = (const float4*)(smem + R_OFF);
    #pragma unroll
    for (int tt = 0; tt < 2; ++tt) {
      float4 rec = recs[ct * 2 + tt];
      float g1 = rec.x, g2 = rec.y;
      int e1 = __float_as_int(rec.z), e2 = __float_as_int(rec.w);
      uint2 o1 = *(const uint2*)(smem + e1 * 4096 + obyte);
      uint2 o2 = *(const uint2*)(smem + e2 * 4096 + obyte);
      unsigned short s1[4] = { (unsigned short)o1.x, (unsigned short)(o1.x >> 16),
                               (unsigned short)o1.y, (unsigned short)(o1.y >> 16) };
      unsigned short s2[4] = { (unsigned short)o2.x, (unsigned short)(o2.x >> 16),
                               (unsigned short)o2.y, (unsigned short)(o2.y >> 16) };
      float* yt = y + (size_t)tt * 4194304 + trow * 64;
      #pragma unroll
      for (int w = 0; w < 4; ++w) {
        // storage col s = 4u+w -> actual col c = w*16 + u
        yt[w * 16 + u] = g1 * bf2f(s1[w]) + g2 * bf2f(s2[w]);
      }
    }
  }
  if (tid < 32) atomicAdd(gacc_out + tid, ((float*)(smem + A_OFF))[tid]);
  __syncthreads();                                   // B5: block's atomics drained

  // ---------- last-block-done: compute cv^2 loss in-kernel ----------
  if (tid == 0) {
    unsigned* cnt = (unsigned*)(gacc_out + 32);
    unsigned old = atomicAdd(cnt, 1u);
    if (old == gridDim.x - 1) {
      float loss = 0.f;
      #pragma unroll
      for (int a = 0; a < 4; ++a) {      // [imp t0][imp t1][load t0][load t1]
        float v[8]; float mm = 0.f;
        #pragma unroll
        for (int i = 0; i < 8; ++i) {
          v[i] = __hip_atomic_load(gacc_out + a * 8 + i, __ATOMIC_RELAXED,
                                   __HIP_MEMORY_SCOPE_AGENT);
          mm += v[i];
        }
        mm *= 0.125f;
        float var = 0.f;
        #pragma unroll
        for (int i = 0; i < 8; ++i) { float d = v[i] - mm; var += d * d; }
        loss += (var * (1.f / 7.f)) / (mm * mm + 1e-10f);
      }
      y[8388608] = 0.01f * loss;
    }
  }
}

// ============================ weight repack ================================
//  w1f: [E][16ks][4n][64lane]       B = W1[k][h], h = n*16+q
//  w2f: [E][2ks][2n][64]            K in H1-sigma order: h = (s&3)*16 + (s>>2)
//  w3f: [E][1][4n][64]              K in H2-sigma order: h = (s&1)*16 + (s>>1)
//  wgt: [16 te][512 k] f32          te = t*8+e (exact copy for fp32 gating)
//  also zeroes gacc[32] + done-counter
__global__ __launch_bounds__(256) void moe_prep(
    const float* __restrict__ W1, const float* __restrict__ W2,
    const float* __restrict__ W3, const float* __restrict__ wg,
    bfrag* __restrict__ w1f, bfrag* __restrict__ w2f,
    bfrag* __restrict__ w3f, float* __restrict__ wgt,
    float* __restrict__ gacc)
{
  int tid = blockIdx.x * 256 + threadIdx.x;
  bfrag o;
  if (tid < 32768) {
    int lane = tid & 63, nt = (tid >> 6) & 3, ks = (tid >> 8) & 15, e = tid >> 12;
    int q = lane & 15, g = lane >> 4;
    int hcol = nt * 16 + q;
    #pragma unroll
    for (int j = 0; j < 8; ++j) {
      int k = ks * 32 + g * 8 + j;
      o[j] = (short)bfbits(W1[((e * 512 + k) * 64) + hcol]);
    }
    w1f[tid] = o;
  } else if (tid < 34816) {
    int idx = tid - 32768;
    int lane = idx & 63, nt = (idx >> 6) & 1, ks = (idx >> 7) & 1, e = idx >> 8;
    int q = lane & 15, g = lane >> 4;
    int n = nt * 16 + q;
    #pragma unroll
    for (int j = 0; j < 8; ++j) {
      int s = ks * 32 + g * 8 + j;
      int hh = (s & 3) * 16 + (s >> 2);
      o[j] = (short)bfbits(W2[(e * 64 + hh) * 32 + n]);
    }
    w2f[idx] = o;
  } else if (tid < 36864) {
    int idx = tid - 34816;
    int lane = idx & 63, nt = (idx >> 6) & 3, e = idx >> 8;
    int q = lane & 15, g = lane >> 4;
    int ocol = nt * 16 + q;
    #pragma unroll
    for (int j = 0; j < 8; ++j) {
      int s = g * 8 + j;
      int hh = (s & 1) * 16 + (s >> 1);
      o[j] = (short)bfbits(W3[(e * 32 + hh) * 64 + ocol]);
    }
    w3f[idx] = o;
  } else if (tid < 45056) {
    int idx = tid - 36864;            // te = idx>>9, k = idx&511
    int te = idx >> 9, k = idx & 511;
    wgt[idx] = wg[(((te >> 3) * 512) + k) * 8 + (te & 7)];
  } else if (tid < 45089) {
    gacc[tid - 45056] = 0.f;          // gacc[0..31] + cnt (word 32)
  }
}

extern "C" void kernel_launch(void* const* d_in, const int* in_sizes, int n_in,
                              void* d_out, int out_size, void* d_ws, size_t ws_size,
                              hipStream_t stream) {
  const float* x  = (const float*)d_in[0];
  const float* wg = (const float*)d_in[1];
  const float* bg = (const float*)d_in[2];
  const float* W1 = (const float*)d_in[3];
  const float* b1 = (const float*)d_in[4];
  const float* W2 = (const float*)d_in[5];
  const float* b2 = (const float*)d_in[6];
  const float* W3 = (const float*)d_in[7];
  const float* b3 = (const float*)d_in[8];
  float* y = (float*)d_out;

  char* ws = (char*)d_ws;
  float*  gacc = (float*)ws;                 // 132 B (32 accum + cnt)
  bfrag*  w1f  = (bfrag*)(ws + 256);         // 524288 B
  bfrag*  w2f  = (bfrag*)(ws + 524544);      // 32768 B
  bfrag*  w3f  = (bfrag*)(ws + 557312);      // 32768 B
  float*  wgt  = (float*)(ws + 590080);      // 32768 B

  moe_prep<<<177, 256, 0, stream>>>(W1, W2, W3, wg, w1f, w2f, w3f, wgt, gacc);
  moe_fused<<<2048, 512, 0, stream>>>(x, bg, wgt, b1, b2, b3, w1f, w2f, w3f, gacc, y);
}

// Round 10
// 104.125 us; speedup vs baseline: 1.2752x; 1.2752x over previous
//
#include <hip/hip_runtime.h>

// ---------------------------------------------------------------------------
// Split Sparse-MMoE forward for MI355X (gfx950), v10.
// B=65536, D=512, E=8, H1=64, H2=32, O=64, T=2, K=2.
//
// moe_prep: weight repack fp32 -> bf16 MFMA B-fragment order (+ wgt fp32
//           transpose, + gacc/cnt zeroing).
// moe_gate: 1024 x 1024. Exact-fp32 gating (wave=k-chunk, lane=token,
//           scalar weights), LDS partial reduce, top-2 softmax -> routing
//           recs (ws) + imp/load atomics + in-kernel cv^2 loss (done-counter).
// moe_main: 2048 x 512 (8 waves = 8 experts), 32 tok/block, LDS 32 KB,
//           3 barriers. Stage x->bf16 in-kernel; 3-layer bf16 MFMA MLP in
//           wave-private LDS chunks; combine using routing recs.
// ---------------------------------------------------------------------------

typedef short bfrag __attribute__((ext_vector_type(8)));   // 8 bf16 = 4 VGPRs
typedef float facc  __attribute__((ext_vector_type(4)));   // 4 f32 accum

#define MFMA16(a, b, c) __builtin_amdgcn_mfma_f32_16x16x32_bf16((a), (b), (c), 0, 0, 0)

__device__ __forceinline__ unsigned short bfbits(float f) {
  unsigned int u = __builtin_bit_cast(unsigned int, f);
  u += 0x7FFFu + ((u >> 16) & 1u);          // RNE
  return (unsigned short)(u >> 16);
}
__device__ __forceinline__ unsigned pack2(float a, float b) {
  return (unsigned)bfbits(a) | ((unsigned)bfbits(b) << 16);
}
__device__ __forceinline__ float bf2f(unsigned short s) {
  unsigned int u = ((unsigned int)s) << 16;
  return __builtin_bit_cast(float, u);
}

// ============================ gating kernel ================================
// LDS: partials [16w][64tok][16te] f32 = 64K; G [64][20] f32 = 5120; lacc 128.
#define GG_OFF   65536
#define GL_OFF   70656
#define GSM_SIZE 70784

__global__ __launch_bounds__(1024, 4) void moe_gate(
    const float* __restrict__ x,
    const float* __restrict__ b_gates,
    const float* __restrict__ wgt,      // [16 te][512 k] f32, te = t*8+e
    float4* __restrict__ routing,       // [B][2 task] {g1,g2,e1,e2}
    float* __restrict__ gacc,           // [32] + cnt at word 32
    float* __restrict__ y)              // loss -> y[8388608]
{
  __shared__ alignas(16) char gsm[GSM_SIZE];
  const int tid = threadIdx.x;
  const int wave = tid >> 6, lane = tid & 63;

  const float* src = x + (size_t)blockIdx.x * 64 * 512 + lane * 512 + wave * 32;
  float4 fr[8];
  #pragma unroll
  for (int j = 0; j < 8; ++j) fr[j] = ((const float4*)src)[j];

  if (tid < 32) ((float*)(gsm + GL_OFF))[tid] = 0.f;

  // exact fp32 partial dots, wave-uniform scalar weights
  {
    int wu = __builtin_amdgcn_readfirstlane(wave);
    const float* wbase = wgt + wu * 32;
    float* pp = (float*)(gsm + wave * 4096 + lane * 64);
    #pragma unroll
    for (int te = 0; te < 16; ++te) {
      const float* wrow = wbase + te * 512;
      float a0 = 0.f, a1 = 0.f, a2 = 0.f, a3 = 0.f;
      #pragma unroll
      for (int j = 0; j < 8; ++j) {
        a0 = fmaf(fr[j].x, wrow[j * 4 + 0], a0);
        a1 = fmaf(fr[j].y, wrow[j * 4 + 1], a1);
        a2 = fmaf(fr[j].z, wrow[j * 4 + 2], a2);
        a3 = fmaf(fr[j].w, wrow[j * 4 + 3], a3);
      }
      pp[(te + lane) & 15] = (a0 + a1) + (a2 + a3);   // te-rotation: conflict-free
    }
  }
  __syncthreads();

  // reduce 16 wave-partials -> logits
  {
    int tok = tid >> 4, te = tid & 15;
    const char* pb = gsm + tok * 64 + (((te + tok) & 15) * 4);
    float s = 0.f;
    #pragma unroll
    for (int w2 = 0; w2 < 16; ++w2) s += *(const float*)(pb + w2 * 4096);
    ((float*)(gsm + GG_OFF))[tok * 20 + te] = s + b_gates[te];
  }
  __syncthreads();

  // top-2 + softmax -> routing + local imp/load accum
  if (tid < 128) {
    int tok = tid >> 1, task = tid & 1;
    const float* Gr = (const float*)(gsm + GG_OFF) + tok * 20 + task * 8;
    float l[8];
    #pragma unroll
    for (int ee = 0; ee < 8; ++ee) l[ee] = Gr[ee];
    float v1 = l[0]; int e1 = 0;
    #pragma unroll
    for (int ee = 1; ee < 8; ++ee) { if (l[ee] > v1) { v1 = l[ee]; e1 = ee; } }
    float v2 = -3.4e38f; int e2 = 0;
    #pragma unroll
    for (int ee = 0; ee < 8; ++ee) {
      if (ee != e1 && l[ee] > v2) { v2 = l[ee]; e2 = ee; }
    }
    float g1 = 1.f / (1.f + __expf(v2 - v1));
    float g2 = 1.f - g1;
    float4 rec;
    rec.x = g1; rec.y = g2;
    rec.z = __int_as_float(e1); rec.w = __int_as_float(e2);
    routing[((size_t)blockIdx.x * 64 + tok) * 2 + task] = rec;
    float* lacc = (float*)(gsm + GL_OFF);
    atomicAdd(lacc + task * 8 + e1, g1);
    atomicAdd(lacc + task * 8 + e2, g2);
    atomicAdd(lacc + 16 + task * 8 + e1, 1.f);
    atomicAdd(lacc + 16 + task * 8 + e2, 1.f);
  }
  __syncthreads();
  if (tid < 32) atomicAdd(gacc + tid, ((float*)(gsm + GL_OFF))[tid]);
  __syncthreads();

  // last-block-done: cv^2 loss
  if (tid == 0) {
    unsigned* cnt = (unsigned*)(gacc + 32);
    unsigned old = atomicAdd(cnt, 1u);
    if (old == gridDim.x - 1) {
      float loss = 0.f;
      #pragma unroll
      for (int a = 0; a < 4; ++a) {      // [imp t0][imp t1][load t0][load t1]
        float v[8]; float mm = 0.f;
        #pragma unroll
        for (int i = 0; i < 8; ++i) {
          v[i] = __hip_atomic_load(gacc + a * 8 + i, __ATOMIC_RELAXED,
                                   __HIP_MEMORY_SCOPE_AGENT);
          mm += v[i];
        }
        mm *= 0.125f;
        float var = 0.f;
        #pragma unroll
        for (int i = 0; i < 8; ++i) { float d = v[i] - mm; var += d * d; }
        loss += (var * (1.f / 7.f)) / (mm * mm + 1e-10f);
      }
      y[8388608] = 0.01f * loss;
    }
  }
}

// ============================ main expert kernel ===========================
// LDS 32 KB: X tile [32 tok][512] bf16 pitch 1024, byte ^= ((r&7)<<4).
// After B1 reused as 8 expert chunks of 4 KB:
//   H1 [32][64]sigma pitch 128 -> H2 [32][32]sigma2 pitch 64 (front 2 KB,
//   own-wave in-order) -> Out [32][64]sigma pitch 128 (full chunk).
__global__ __launch_bounds__(512, 6) void moe_main(
    const float* __restrict__ x,
    const float* __restrict__ b1,
    const float* __restrict__ b2,
    const float* __restrict__ b3,
    const bfrag* __restrict__ w1f,
    const bfrag* __restrict__ w2f,
    const bfrag* __restrict__ w3f,
    const float4* __restrict__ routing,
    float* __restrict__ y)
{
  __shared__ alignas(16) char smem[32768];
  const int tid = threadIdx.x;
  const int wave = tid >> 6, lane = tid & 63;
  const int q = lane & 15, g = lane >> 4;
  const int e = wave;                       // 8 waves = 8 experts
  const unsigned cb = (unsigned)e * 4096u;  // own chunk

  // ---------------- stage X: fp32 -> bf16 LDS (low register pressure) ------
  {
    const float* xblk = x + (size_t)blockIdx.x * 32 * 512;
    #pragma unroll 4
    for (int it = 0; it < 8; ++it) {
      int idx = it * 2048 + tid * 4;
      float4 v = *(const float4*)(xblk + idx);
      int r = idx >> 9, c = idx & 511;
      unsigned byte = ((unsigned)(r * 1024 + c * 2)) ^ ((unsigned)(r & 7) << 4);
      uint2 p; p.x = pack2(v.x, v.y); p.y = pack2(v.z, v.w);
      *(uint2*)(smem + byte) = p;
    }
  }
  __syncthreads();                                   // B0: X staged

  // ---------------- GEMM1: 32 tok x 64 h1, K=512 ----------------
  facc acc[2][4];
  #pragma unroll
  for (int m = 0; m < 2; ++m)
    #pragma unroll
    for (int n = 0; n < 4; ++n) acc[m][n] = (facc)0.f;

  const bfrag* w1e = w1f + e * 4096 + lane;
  #pragma unroll
  for (int ks = 0; ks < 16; ++ks) {
    bfrag B0 = w1e[ks * 256];
    bfrag B1 = w1e[ks * 256 + 64];
    bfrag B2 = w1e[ks * 256 + 128];
    bfrag B3 = w1e[ks * 256 + 192];
    #pragma unroll
    for (int m = 0; m < 2; ++m) {
      unsigned ba = ((unsigned)((m * 16 + q) * 1024 + ks * 64 + g * 16)) ^ ((unsigned)(q & 7) << 4);
      bfrag A = *(const bfrag*)(smem + ba);
      acc[m][0] = MFMA16(A, B0, acc[m][0]);
      acc[m][1] = MFMA16(A, B1, acc[m][1]);
      acc[m][2] = MFMA16(A, B2, acc[m][2]);
      acc[m][3] = MFMA16(A, B3, acc[m][3]);
    }
  }

  // preload GEMM2 weights + bias (in flight across barrier + H1 phase)
  bfrag W2r[4];
  #pragma unroll
  for (int i = 0; i < 4; ++i) W2r[i] = w2f[e * 256 + i * 64 + lane];
  float b2v0 = b2[e * 32 + q];
  float b2v1 = b2[e * 32 + 16 + q];
  __syncthreads();                                   // B1: X dead

  // ---------------- H1 -> own chunk (sigma: s = q*4+n) ----------------
  {
    float bv[4];
    #pragma unroll
    for (int n = 0; n < 4; ++n) bv[n] = b1[e * 64 + n * 16 + q];
    #pragma unroll
    for (int m = 0; m < 2; ++m) {
      #pragma unroll
      for (int j = 0; j < 4; ++j) {
        float v0 = fmaxf(acc[m][0][j] + bv[0], 0.f);
        float v1 = fmaxf(acc[m][1][j] + bv[1], 0.f);
        float v2 = fmaxf(acc[m][2][j] + bv[2], 0.f);
        float v3 = fmaxf(acc[m][3][j] + bv[3], 0.f);
        int rr = m * 16 + g * 4 + j;
        unsigned byte = cb + (((unsigned)(rr * 128 + q * 8)) ^ ((unsigned)(rr & 7) << 4));
        uint2 pk; pk.x = pack2(v0, v1); pk.y = pack2(v2, v3);
        *(uint2*)(smem + byte) = pk;
      }
    }
  }

  // ---------------- GEMM2: K=64 (sigma), N=32 ----------------
  {
    facc a2[2][2];
    #pragma unroll
    for (int m = 0; m < 2; ++m) { a2[m][0] = (facc)0.f; a2[m][1] = (facc)0.f; }
    #pragma unroll
    for (int ks = 0; ks < 2; ++ks) {
      #pragma unroll
      for (int m = 0; m < 2; ++m) {
        unsigned ba = cb + (((unsigned)((m * 16 + q) * 128 + ks * 64 + g * 16)) ^ ((unsigned)(q & 7) << 4));
        bfrag A = *(const bfrag*)(smem + ba);
        a2[m][0] = MFMA16(A, W2r[ks * 2], a2[m][0]);
        a2[m][1] = MFMA16(A, W2r[ks * 2 + 1], a2[m][1]);
      }
    }
    // preload GEMM3 weights + bias
    bfrag W3r[4];
    #pragma unroll
    for (int n = 0; n < 4; ++n) W3r[n] = w3f[e * 256 + n * 64 + lane];
    float b3v[4];
    #pragma unroll
    for (int n = 0; n < 4; ++n) b3v[n] = b3[e * 64 + n * 16 + q];

    // H2 -> own chunk front (sigma2: s = q*2+n)
    #pragma unroll
    for (int m = 0; m < 2; ++m) {
      #pragma unroll
      for (int j = 0; j < 4; ++j) {
        float v0 = fmaxf(a2[m][0][j] + b2v0, 0.f);
        float v1 = fmaxf(a2[m][1][j] + b2v1, 0.f);
        int rr = m * 16 + g * 4 + j;
        unsigned byte = cb + (((unsigned)(rr * 64 + q * 4)) ^ ((unsigned)(rr & 7) << 4));
        *(unsigned int*)(smem + byte) = pack2(v0, v1);
      }
    }

    // ---------------- GEMM3: K=32 (sigma2), N=64 ----------------
    facc a3[2][4];
    #pragma unroll
    for (int m = 0; m < 2; ++m)
      #pragma unroll
      for (int n = 0; n < 4; ++n) a3[m][n] = (facc)0.f;
    #pragma unroll
    for (int m = 0; m < 2; ++m) {
      unsigned ba = cb + (((unsigned)((m * 16 + q) * 64 + g * 16)) ^ ((unsigned)(q & 7) << 4));
      bfrag A = *(const bfrag*)(smem + ba);
      #pragma unroll
      for (int n = 0; n < 4; ++n) a3[m][n] = MFMA16(A, W3r[n], a3[m][n]);
    }
    // Out -> full own chunk (sigma: s = q*4+n), after all H2 reads (in-order)
    #pragma unroll
    for (int m = 0; m < 2; ++m) {
      #pragma unroll
      for (int j = 0; j < 4; ++j) {
        float v0 = fmaxf(a3[m][0][j] + b3v[0], 0.f);
        float v1 = fmaxf(a3[m][1][j] + b3v[1], 0.f);
        float v2 = fmaxf(a3[m][2][j] + b3v[2], 0.f);
        float v3 = fmaxf(a3[m][3][j] + b3v[3], 0.f);
        int rr = m * 16 + g * 4 + j;
        unsigned byte = cb + (((unsigned)(rr * 128 + q * 8)) ^ ((unsigned)(rr & 7) << 4));
        uint2 pk; pk.x = pack2(v0, v1); pk.y = pack2(v2, v3);
        *(uint2*)(smem + byte) = pk;
      }
    }
  }
  __syncthreads();                                   // B2: chunks complete

  // ---------------- combine: routing recs + weighted sum ----------------
  {
    int tok = tid >> 4, u = tid & 15;
    size_t trow = (size_t)blockIdx.x * 32 + tok;
    unsigned obyte = ((unsigned)(tok * 128 + u * 8)) ^ ((unsigned)(tok & 7) << 4);
    #pragma unroll
    for (int tt = 0; tt < 2; ++tt) {
      float4 rec = routing[trow * 2 + tt];
      float g1 = rec.x, g2 = rec.y;
      int e1 = __float_as_int(rec.z), e2 = __float_as_int(rec.w);
      uint2 o1 = *(const uint2*)(smem + e1 * 4096 + obyte);
      uint2 o2 = *(const uint2*)(smem + e2 * 4096 + obyte);
      unsigned short s1[4] = { (unsigned short)o1.x, (unsigned short)(o1.x >> 16),
                               (unsigned short)o1.y, (unsigned short)(o1.y >> 16) };
      unsigned short s2[4] = { (unsigned short)o2.x, (unsigned short)(o2.x >> 16),
                               (unsigned short)o2.y, (unsigned short)(o2.y >> 16) };
      float* yt = y + (size_t)tt * 4194304 + trow * 64;
      #pragma unroll
      for (int w = 0; w < 4; ++w) {
        // storage col s = 4u+w -> actual col c = w*16 + u
        yt[w * 16 + u] = g1 * bf2f(s1[w]) + g2 * bf2f(s2[w]);
      }
    }
  }
}

// ============================ weight repack ================================
//  w1f: [E][16ks][4n][64lane]       B = W1[k][h], h = n*16+q
//  w2f: [E][2ks][2n][64]            K in H1-sigma order: h = (s&3)*16 + (s>>2)
//  w3f: [E][1][4n][64]              K in H2-sigma order: h = (s&1)*16 + (s>>1)
//  wgt: [16 te][512 k] f32          te = t*8+e (exact copy for fp32 gating)
//  also zeroes gacc[32] + done-counter
__global__ __launch_bounds__(256) void moe_prep(
    const float* __restrict__ W1, const float* __restrict__ W2,
    const float* __restrict__ W3, const float* __restrict__ wg,
    bfrag* __restrict__ w1f, bfrag* __restrict__ w2f,
    bfrag* __restrict__ w3f, float* __restrict__ wgt,
    float* __restrict__ gacc)
{
  int tid = blockIdx.x * 256 + threadIdx.x;
  bfrag o;
  if (tid < 32768) {
    int lane = tid & 63, nt = (tid >> 6) & 3, ks = (tid >> 8) & 15, e = tid >> 12;
    int q = lane & 15, g = lane >> 4;
    int hcol = nt * 16 + q;
    #pragma unroll
    for (int j = 0; j < 8; ++j) {
      int k = ks * 32 + g * 8 + j;
      o[j] = (short)bfbits(W1[((e * 512 + k) * 64) + hcol]);
    }
    w1f[tid] = o;
  } else if (tid < 34816) {
    int idx = tid - 32768;
    int lane = idx & 63, nt = (idx >> 6) & 1, ks = (idx >> 7) & 1, e = idx >> 8;
    int q = lane & 15, g = lane >> 4;
    int n = nt * 16 + q;
    #pragma unroll
    for (int j = 0; j < 8; ++j) {
      int s = ks * 32 + g * 8 + j;
      int hh = (s & 3) * 16 + (s >> 2);
      o[j] = (short)bfbits(W2[(e * 64 + hh) * 32 + n]);
    }
    w2f[idx] = o;
  } else if (tid < 36864) {
    int idx = tid - 34816;
    int lane = idx & 63, nt = (idx >> 6) & 3, e = idx >> 8;
    int q = lane & 15, g = lane >> 4;
    int ocol = nt * 16 + q;
    #pragma unroll
    for (int j = 0; j < 8; ++j) {
      int s = g * 8 + j;
      int hh = (s & 1) * 16 + (s >> 1);
      o[j] = (short)bfbits(W3[(e * 32 + hh) * 64 + ocol]);
    }
    w3f[idx] = o;
  } else if (tid < 45056) {
    int idx = tid - 36864;            // te = idx>>9, k = idx&511
    int te = idx >> 9, k = idx & 511;
    wgt[idx] = wg[(((te >> 3) * 512) + k) * 8 + (te & 7)];
  } else if (tid < 45089) {
    gacc[tid - 45056] = 0.f;          // gacc[0..31] + cnt (word 32)
  }
}

extern "C" void kernel_launch(void* const* d_in, const int* in_sizes, int n_in,
                              void* d_out, int out_size, void* d_ws, size_t ws_size,
                              hipStream_t stream) {
  const float* x  = (const float*)d_in[0];
  const float* wg = (const float*)d_in[1];
  const float* bg = (const float*)d_in[2];
  const float* W1 = (const float*)d_in[3];
  const float* b1 = (const float*)d_in[4];
  const float* W2 = (const float*)d_in[5];
  const float* b2 = (const float*)d_in[6];
  const float* W3 = (const float*)d_in[7];
  const float* b3 = (const float*)d_in[8];
  float* y = (float*)d_out;

  char* ws = (char*)d_ws;
  float*  gacc    = (float*)ws;                 // 132 B (32 accum + cnt)
  bfrag*  w1f     = (bfrag*)(ws + 256);         // 524288 B
  bfrag*  w2f     = (bfrag*)(ws + 524544);      // 32768 B
  bfrag*  w3f     = (bfrag*)(ws + 557312);      // 32768 B
  float*  wgt     = (float*)(ws + 590080);      // 32768 B
  float4* routing = (float4*)(ws + 622848);     // 2097152 B

  moe_prep<<<177, 256, 0, stream>>>(W1, W2, W3, wg, w1f, w2f, w3f, wgt, gacc);
  moe_gate<<<1024, 1024, 0, stream>>>(x, bg, wgt, routing, gacc, y);
  moe_main<<<2048, 512, 0, stream>>>(x, b1, b2, b3, w1f, w2f, w3f, routing, y);
}